// Round 13
// baseline (258.925 us; speedup 1.0000x reference)
//
#include <hip/hip_runtime.h>

typedef unsigned short u16;
typedef unsigned int u32;

constexpr int kNV  = 40962;
constexpr int kNF  = 81920;
constexpr int kNVP = 10242;
constexpr int kB   = 2;
constexpr float kEPS  = 1e-5f;
constexpr int kBNN   = kB * kNV;              // 81924
constexpr float kInvN = 1.0f / (float)kBNN;
constexpr int kTiles = (kBNN + 15) / 16;      // 5121

typedef __attribute__((ext_vector_type(8))) short bf16x8;
typedef __attribute__((ext_vector_type(4))) float f32x4;
union U4 { uint4 u; bf16x8 h; };

__device__ __forceinline__ float bflo(u32 u) { return __uint_as_float(u << 16); }
__device__ __forceinline__ float bfhi(u32 u) { return __uint_as_float(u & 0xffff0000u); }
__device__ __forceinline__ u32 packbf(float a, float b) {
    u32 ua = __float_as_uint(a), ub = __float_as_uint(b);
    ua += 0x7fffu + ((ua >> 16) & 1u);
    ub += 0x7fffu + ((ub >> 16) & 1u);
    return (ua >> 16) | (ub & 0xffff0000u);
}
__device__ __forceinline__ u16 bf16r(float a) {
    u32 ua = __float_as_uint(a);
    ua += 0x7fffu + ((ua >> 16) & 1u);
    return (u16)(ua >> 16);
}
__device__ __forceinline__ float b2f(u16 u) { return __uint_as_float(((u32)u) << 16); }

// Layout convention this round: all per-task activation arrays are BATCH-INTERLEAVED:
//   row r = v*2 + b   (vertex arrays, (NV,B,64)/(NV,B,128))
//   row rf = f*2 + b  (face array gegn, (NF,B,64))
// so a gather of logical index v/f touches ONE contiguous 256B/512B region covering both
// batches instead of two scattered 128B/256B lines (indices are batch-shared).

// ---------------- zero stats ----------------
__global__ void zero_stats_k(float* stats) {
    int t = threadIdx.x;
    if (t < 512) stats[t] = 0.f;
}

// ---------------- build face table: {col, Gv*ew, Gv*ns, 0} per (face, jk) ----------------
__global__ __launch_bounds__(256) void build_facetab_k(
    const int* __restrict__ Gc, const float* __restrict__ Gv,
    const float* __restrict__ ew, const float* __restrict__ ns,
    uint4* __restrict__ tab)
{
    int idx = blockIdx.x * 256 + threadIdx.x;       // kNF*9 total
    if (idx >= kNF * 9) return;
    int f = idx / 9, jk = idx - f * 9;
    int j = jk / 3, k = jk - j * 3;
    int r = j * kNF + f;
    float gv = Gv[r * 3 + k];
    tab[idx] = make_uint4((u32)Gc[r * 3 + k],
                          __float_as_uint(gv * ew[f * 3 + j]),
                          __float_as_uint(gv * ns[f * 3 + j]), 0u);
}

// ---------------- build vertex table: 128B/vertex, 16B-aligned idx+weight blocks ----------------
__global__ __launch_bounds__(256) void build_vtab_k(
    const int* __restrict__ Lc, const float* __restrict__ Lv,
    const int* __restrict__ Fc, const float* __restrict__ Fv,
    u32* __restrict__ vtab)
{
    int v = blockIdx.x * 256 + threadIdx.x;
    if (v >= kNV) return;
    u32* d = vtab + (size_t)v * 32;
#pragma unroll
    for (int k = 0; k < 7; ++k) {
        d[k]      = (u32)Lc[v * 7 + k];
        d[16 + k] = __float_as_uint(Lv[v * 7 + k]);
    }
#pragma unroll
    for (int k = 0; k < 6; ++k) {
        d[7 + k]  = (u32)Fc[v * 6 + k];
        d[23 + k] = __float_as_uint(Fv[v * 6 + k]);
    }
    d[13] = 0; d[14] = 0; d[15] = 0;
    d[29] = 0; d[30] = 0; d[31] = 0;
}

// ---------------- pack meshconv coeffs (64,64,4) -> global MFMA B-fragment table (32 KB) ----------------
__global__ __launch_bounds__(256) void pack_coeffs_k(const float* __restrict__ coeffs,
                                                     u16* __restrict__ Bg)
{
    int idx = blockIdx.x * 256 + threadIdx.x;       // 256*64 total
    if (idx >= 256 * 64) return;
    int k = idx >> 6, col = idx & 63;
    int s = k >> 5, kg = (k >> 3) & 3, jj = k & 7;
    Bg[((s * 4 + kg) * 64 + col) * 8 + jj] =
        bf16r(coeffs[((size_t)col * 64 + (k >> 2)) * 4 + (k & 3)]);
}

// ---------------- tiled transpose: x1 -> xin16 (ones-pad) bf16, x2 -> Xc[:, :64] bf16 ----------------
__global__ __launch_bounds__(256) void transpose_in_k(const float* __restrict__ x1,
                                                      const float* __restrict__ x2,
                                                      u16* __restrict__ xin16,
                                                      u16* __restrict__ Xc) {
    __shared__ float t1[64 * 65];
    __shared__ float t2[64 * 65];
    const int tilesPerB = (kNV + 63) / 64;  // 641
    int tile = blockIdx.x % tilesPerB;
    int b    = blockIdx.x / tilesPerB;
    int v0   = tile * 64;
    int tid  = threadIdx.x;
    bool hasX1 = v0 < kNVP;
#pragma unroll
    for (int r = 0; r < 16; ++r) {
        int idx = r * 256 + tid;
        int c = idx >> 6, vl = idx & 63;
        int v = v0 + vl;
        if (v < kNV) {
            t2[vl * 65 + c] = x2[(size_t)(b * 64 + c) * kNV + v];
            if (hasX1) t1[vl * 65 + c] = (v < kNVP) ? x1[(size_t)(b * 64 + c) * kNVP + v] : 1.0f;
        }
    }
    __syncthreads();
#pragma unroll
    for (int r = 0; r < 16; ++r) {
        int idx = r * 256 + tid;
        int vl = idx >> 6, c = idx & 63;
        int v = v0 + vl;
        if (v < kNV) {
            Xc[((size_t)v * 2 + b) * 128 + c]   = bf16r(t2[vl * 65 + c]);
            xin16[((size_t)v * 2 + b) * 64 + c] = hasX1 ? bf16r(t1[vl * 65 + c]) : (u16)0x3f80;
        }
    }
}

// ---------------- face kernel: tasks rf=f*2+b, 4 tasks/p (2 faces x 2 batches), 4ch/lane ----------------
template <bool BN>
__global__ __launch_bounds__(256) void face_k(
    const u16* __restrict__ src,                                     // (NV,B,64) bf16
    const uint4* __restrict__ tab,                                   // (NF*9)
    const float* __restrict__ st, const float* __restrict__ bg, const float* __restrict__ bb,
    u32* __restrict__ gegn)                                          // (NF,B,64) bf16x2
{
    int lane = threadIdx.x & 63;
    int q  = lane >> 4;
    int c0 = 4 * (lane & 15);
    int wave = blockIdx.x * 4 + (threadIdx.x >> 6);
    int nW   = gridDim.x * 4;
    float sc[4], sh[4];
    if constexpr (BN) {
#pragma unroll
        for (int j = 0; j < 4; ++j) {
            float m   = st[c0 + j] * kInvN;
            float var = st[64 + c0 + j] * kInvN - m * m;
            sc[j] = bg[c0 + j] * rsqrtf(var + kEPS);
            sh[j] = bb[c0 + j] - m * sc[j];
        }
    }
    const int nG = (kB * kNF) / 16;  // 10240, exact
    for (int g = wave; g < nG; g += nW) {
        int t0 = g * 16;
#pragma unroll
        for (int p = 0; p < 4; ++p) {
            int task = t0 + 4 * p + q;                // rf = f*2 + b
            int b = task & 1;
            int f = task >> 1;
            const uint4* tf = tab + (size_t)f * 9;
            float aE[4] = {0.f, 0.f, 0.f, 0.f}, aN[4] = {0.f, 0.f, 0.f, 0.f};
#pragma unroll
            for (int jk = 0; jk < 9; ++jk) {
                uint4 tb = tf[jk];
                float wE = __uint_as_float(tb.y), wN = __uint_as_float(tb.z);
                uint2 xv = *(const uint2*)&src[((size_t)tb.x * 2 + b) * 64 + c0];
                float x_[4] = {bflo(xv.x), bfhi(xv.x), bflo(xv.y), bfhi(xv.y)};
#pragma unroll
                for (int j = 0; j < 4; ++j) {
                    float x = x_[j];
                    if constexpr (BN) { x = fmaf(x, sc[j], sh[j]); x = x > 0.f ? x : 0.f; }
                    aE[j] = fmaf(wE, x, aE[j]);
                    aN[j] = fmaf(wN, x, aN[j]);
                }
            }
            *(uint4*)&gegn[(size_t)task * 64 + c0] =
                make_uint4(packbf(aE[0], aN[0]), packbf(aE[1], aN[1]),
                           packbf(aE[2], aN[2]), packbf(aE[3], aN[3]));
        }
    }
}

// ---------------- fused vertex kernel: tasks r=v*2+b (2 tasks/p = 1 vertex, both batches) ----------------
// Each gather instruction now touches ONE contiguous 256B (src) / 512B-half (gegn) region.
template <bool STATS, bool BN, bool OUT16>
__global__ __launch_bounds__(256, 2) void vertex_fused_k(
    const u16* __restrict__ src,                                     // (NV,B,64) bf16
    const u32* __restrict__ gegn,                                    // (NF,B,64)
    const u32* __restrict__ vtab,                                    // (NV,32) packed idx/w
    const uint4* __restrict__ Bg,                                    // packed B fragments (32 KB)
    const float* __restrict__ bias,
    const float* __restrict__ st, const float* __restrict__ bg, const float* __restrict__ bbn,
    void* __restrict__ out_, int outStride, float* __restrict__ stats)
{
    __shared__ __align__(16) uint2 feat[4][16][64];   // 32 KB
    __shared__ float sred[STATS ? 4 * 128 : 4];
    int tid   = threadIdx.x;
    int lane  = tid & 63;
    int cl = lane & 31, half = lane >> 5;
    int c0 = 2 * cl;
    int wslot = tid >> 6;
    float sc0 = 0.f, sh0 = 0.f, sc1 = 0.f, sh1 = 0.f;
    if constexpr (BN) {
        float m0 = st[c0] * kInvN, m1 = st[c0 + 1] * kInvN;
        float v0 = st[64 + c0] * kInvN - m0 * m0;
        float v1 = st[64 + c0 + 1] * kInvN - m1 * m1;
        sc0 = bg[c0] * rsqrtf(v0 + kEPS);     sh0 = bbn[c0] - m0 * sc0;
        sc1 = bg[c0 + 1] * rsqrtf(v1 + kEPS); sh1 = bbn[c0 + 1] - m1 * sc1;
    }
    int tA = lane & 15, kg = lane >> 4;
    const int amask = (tA & 3) << 3;
    float bias_w[4];
#pragma unroll
    for (int nf = 0; nf < 4; ++nf) bias_w[nf] = bias[nf * 16 + tA];
    float s_[4] = {0.f, 0.f, 0.f, 0.f}, sq_[4] = {0.f, 0.f, 0.f, 0.f};

    int wave = blockIdx.x * 4 + wslot;
    int nW   = gridDim.x * 4;

    for (int tile = wave; tile < kTiles; tile += nW) {
        int base = tile * 16;
        // ---- gather phase: 2 channels/lane; the 2 tasks per p share vertex v (b=half) ----
#pragma unroll 4
        for (int p = 0; p < 8; ++p) {
            int t = 2 * p + half;
            int task = base + t;                     // r = v*2 + b
            float x0 = 0.f, x1 = 0.f, l0 = 0.f, l1 = 0.f;
            float e0 = 0.f, e1 = 0.f, n0 = 0.f, n1 = 0.f;
            if (task < kBNN) {
                int b = task & 1;
                int v = task >> 1;
                const u32* vt = vtab + (size_t)v * 32;
                uint4  I0 = *(const uint4*)&vt[0];     // Lc0-3
                uint4  I1 = *(const uint4*)&vt[4];     // Lc4-6, Fc0
                uint4  I2 = *(const uint4*)&vt[8];     // Fc1-4
                u32    I3 = vt[12];                    // Fc5
                float4 W0 = *(const float4*)&vt[16];   // Lv0-3
                float4 W1 = *(const float4*)&vt[20];   // Lv4-6, Fv0
                float4 W2 = *(const float4*)&vt[24];   // Fv1-4
                float  W3 = __uint_as_float(vt[28]);   // Fv5
                u32 Lcols[7] = {I0.x, I0.y, I0.z, I0.w, I1.x, I1.y, I1.z};
                float Lw[7]  = {W0.x, W0.y, W0.z, W0.w, W1.x, W1.y, W1.z};
                u32 Fcols[6] = {I1.w, I2.x, I2.y, I2.z, I2.w, I3};
                float Fw[6]  = {W1.w, W2.x, W2.y, W2.z, W2.w, W3};

                u32 xv = *(const u32*)&src[(size_t)task * 64 + c0];
                x0 = bflo(xv); x1 = bfhi(xv);
                if constexpr (BN) {
                    x0 = fmaf(x0, sc0, sh0); x0 = x0 > 0.f ? x0 : 0.f;
                    x1 = fmaf(x1, sc1, sh1); x1 = x1 > 0.f ? x1 : 0.f;
                }
#pragma unroll
                for (int k = 0; k < 7; ++k) {
                    u32 lv = *(const u32*)&src[((size_t)Lcols[k] * 2 + b) * 64 + c0];
                    float w = Lw[k];
                    float y0 = bflo(lv), y1 = bfhi(lv);
                    if constexpr (BN) {
                        y0 = fmaf(y0, sc0, sh0); y0 = y0 > 0.f ? y0 : 0.f;
                        y1 = fmaf(y1, sc1, sh1); y1 = y1 > 0.f ? y1 : 0.f;
                    }
                    l0 = fmaf(w, y0, l0); l1 = fmaf(w, y1, l1);
                }
#pragma unroll
                for (int k = 0; k < 6; ++k) {
                    uint2 gv = *(const uint2*)&gegn[((size_t)Fcols[k] * 2 + b) * 64 + c0];
                    float w = Fw[k];
                    e0 = fmaf(w, bflo(gv.x), e0); n0 = fmaf(w, bfhi(gv.x), n0);
                    e1 = fmaf(w, bflo(gv.y), e1); n1 = fmaf(w, bfhi(gv.y), n1);
                }
            }
            int cs = c0 ^ ((t & 3) << 3);
            *(uint4*)&feat[wslot][t][cs] =
                make_uint4(packbf(x0, l0), packbf(e0, n0), packbf(x1, l1), packbf(e1, n1));
        }
        // ---- MFMA phase: A from LDS (intra-wave, no barrier), B from global (L1/L2-hot) ----
        f32x4 z = {0.f, 0.f, 0.f, 0.f};
        f32x4 acc[4]; acc[0] = z; acc[1] = z; acc[2] = z; acc[3] = z;
#pragma unroll
        for (int sl = 0; sl < 8; ++sl) {
            int i0 = sl * 8 + kg * 2;
            U4 a; a.u = *(const uint4*)&feat[wslot][tA][i0 ^ amask];
#pragma unroll
            for (int nf = 0; nf < 4; ++nf) {
                U4 bb; bb.u = Bg[(sl * 4 + kg) * 64 + nf * 16 + tA];
                acc[nf] = __builtin_amdgcn_mfma_f32_16x16x32_bf16(a.h, bb.h, acc[nf], 0, 0, 0);
            }
        }
        // ---- write: D row = kg*4+r, col = nf*16+tA ----
#pragma unroll
        for (int nf = 0; nf < 4; ++nf) {
#pragma unroll
            for (int r = 0; r < 4; ++r) {
                int task = base + kg * 4 + r;
                if (task < kBNN) {
                    float val = acc[nf][r] + bias_w[nf];
                    int col = nf * 16 + tA;
                    if constexpr (OUT16)
                        ((u16*)out_)[(size_t)task * outStride + col] = bf16r(val);
                    else
                        ((float*)out_)[(size_t)task * outStride + col] = val;
                    if constexpr (STATS) { s_[nf] += val; sq_[nf] += val * val; }
                }
            }
        }
    }
    if constexpr (STATS) {
#pragma unroll
        for (int nf = 0; nf < 4; ++nf) {
            s_[nf]  += __shfl_xor(s_[nf], 16, 64);  s_[nf]  += __shfl_xor(s_[nf], 32, 64);
            sq_[nf] += __shfl_xor(sq_[nf], 16, 64); sq_[nf] += __shfl_xor(sq_[nf], 32, 64);
        }
        if (lane < 16) {
#pragma unroll
            for (int nf = 0; nf < 4; ++nf) {
                sred[wslot * 128 + nf * 16 + lane]      = s_[nf];
                sred[wslot * 128 + 64 + nf * 16 + lane] = sq_[nf];
            }
        }
        __syncthreads();
        if (wslot == 0) {
            float S = 0.f, SQ = 0.f;
#pragma unroll
            for (int w = 0; w < 4; ++w) {
                S  += sred[w * 128 + lane];
                SQ += sred[w * 128 + 64 + lane];
            }
            atomicAdd(&stats[lane], S);
            atomicAdd(&stats[64 + lane], SQ);
        }
    }
}

// ---------------- conv1+convs fused: A=Xc bf16 global, N=128 (64|64), K=128, MFMA ----------------
__global__ __launch_bounds__(512) void pconv_dual_k(
    const u16* __restrict__ Xc,
    const float* __restrict__ W1, const float* __restrict__ b1,
    const float* __restrict__ W2, const float* __restrict__ b2,
    u16* __restrict__ O1, u16* __restrict__ O2,
    float* __restrict__ stats1, float* __restrict__ stats2)
{
    __shared__ __align__(16) u16 Bl[128 * 128];   // 32 KB
    __shared__ float sred[8 * 256];
    int tid = threadIdx.x;
    for (int idx = tid; idx < 128 * 128; idx += 512) {
        int k = idx >> 7, col = idx & 127;
        int s = k >> 5, kg = (k >> 3) & 3, jj = k & 7;
        float v = (col < 64) ? W1[(size_t)col * 128 + k] : W2[(size_t)(col - 64) * 128 + k];
        Bl[((s * 4 + kg) * 128 + (col ^ kg)) * 8 + jj] = bf16r(v);
    }
    __syncthreads();

    int lane = tid & 63, wslot = tid >> 6;
    int tA = lane & 15, kg = lane >> 4;
    float bias_w[8];
#pragma unroll
    for (int nf = 0; nf < 8; ++nf)
        bias_w[nf] = (nf < 4) ? b1[nf * 16 + tA] : b2[(nf - 4) * 16 + tA];
    float s_[8] = {0.f}, sq_[8] = {0.f};

    int wave = blockIdx.x * 8 + wslot;
    int nW   = gridDim.x * 8;
    for (int tile = wave; tile < kTiles; tile += nW) {
        int base = tile * 16;
        int taskA = min(base + tA, kBNN - 1);
        f32x4 zz = {0.f, 0.f, 0.f, 0.f};
        f32x4 acc[8];
#pragma unroll
        for (int nf = 0; nf < 8; ++nf) acc[nf] = zz;
#pragma unroll
        for (int s = 0; s < 4; ++s) {
            U4 a; a.u = *(const uint4*)&Xc[(size_t)taskA * 128 + s * 32 + kg * 8];
#pragma unroll
            for (int nf = 0; nf < 8; ++nf) {
                int colb = nf * 16 + tA;
                U4 bb; bb.u = *(const uint4*)&Bl[((s * 4 + kg) * 128 + (colb ^ kg)) * 8];
                acc[nf] = __builtin_amdgcn_mfma_f32_16x16x32_bf16(a.h, bb.h, acc[nf], 0, 0, 0);
            }
        }
#pragma unroll
        for (int nf = 0; nf < 8; ++nf) {
#pragma unroll
            for (int r = 0; r < 4; ++r) {
                int task = base + kg * 4 + r;
                if (task < kBNN) {
                    float val = acc[nf][r] + bias_w[nf];
                    if (nf < 4) O1[(size_t)task * 64 + nf * 16 + tA] = bf16r(val);
                    else        O2[(size_t)task * 64 + (nf - 4) * 16 + tA] = bf16r(val);
                    s_[nf] += val; sq_[nf] += val * val;
                }
            }
        }
    }
#pragma unroll
    for (int nf = 0; nf < 8; ++nf) {
        s_[nf]  += __shfl_xor(s_[nf], 16, 64);  s_[nf]  += __shfl_xor(s_[nf], 32, 64);
        sq_[nf] += __shfl_xor(sq_[nf], 16, 64); sq_[nf] += __shfl_xor(sq_[nf], 32, 64);
    }
    if (lane < 16) {
#pragma unroll
        for (int nf = 0; nf < 8; ++nf) {
            sred[wslot * 256 + nf * 16 + lane]       = s_[nf];
            sred[wslot * 256 + 128 + nf * 16 + lane] = sq_[nf];
        }
    }
    __syncthreads();
    if (wslot == 0) {
        float S = 0.f, SQ = 0.f;
#pragma unroll
        for (int w = 0; w < 8; ++w) {
            S  += sred[w * 256 + lane];
            SQ += sred[w * 256 + 128 + lane];
        }
        atomicAdd(&stats1[lane], S);
        atomicAdd(&stats1[64 + lane], SQ);
    } else if (wslot == 1) {
        float S = 0.f, SQ = 0.f;
#pragma unroll
        for (int w = 0; w < 8; ++w) {
            S  += sred[w * 256 + 64 + lane];
            SQ += sred[w * 256 + 128 + 64 + lane];
        }
        atomicAdd(&stats2[lane], S);
        atomicAdd(&stats2[64 + lane], SQ);
    }
}

// ---------------- conv3: A = relu(bn2(P2 bf16)) on the fly, K=64, N=64, MFMA ----------------
__global__ __launch_bounds__(512) void pconv3_k(
    const u16* __restrict__ P2,
    const float* __restrict__ st2, const float* __restrict__ g2, const float* __restrict__ b2n,
    const float* __restrict__ W, const float* __restrict__ bW,
    u16* __restrict__ O, float* __restrict__ stats)
{
    __shared__ __align__(16) u16 Bl[64 * 64];   // 8 KB
    __shared__ float sred[8 * 128];
    int tid = threadIdx.x;
    for (int idx = tid; idx < 64 * 64; idx += 512) {
        int k = idx >> 6, col = idx & 63;
        int s = k >> 5, kg = (k >> 3) & 3, jj = k & 7;
        Bl[((s * 4 + kg) * 64 + (col ^ kg)) * 8 + jj] = bf16r(W[(size_t)col * 64 + k]);
    }
    __syncthreads();

    int lane = tid & 63, wslot = tid >> 6;
    int tA = lane & 15, kg = lane >> 4;
    float scA[2][8], shA[2][8];
#pragma unroll
    for (int s = 0; s < 2; ++s)
#pragma unroll
        for (int j = 0; j < 8; ++j) {
            int ch = s * 32 + kg * 8 + j;
            float m   = st2[ch] * kInvN;
            float var = st2[64 + ch] * kInvN - m * m;
            float sc  = g2[ch] * rsqrtf(var + kEPS);
            scA[s][j] = sc;
            shA[s][j] = b2n[ch] - m * sc;
        }
    float bias_w[4];
#pragma unroll
    for (int nf = 0; nf < 4; ++nf) bias_w[nf] = bW[nf * 16 + tA];
    float s_[4] = {0.f}, sq_[4] = {0.f};

    int wave = blockIdx.x * 8 + wslot;
    int nW   = gridDim.x * 8;
    for (int tile = wave; tile < kTiles; tile += nW) {
        int base = tile * 16;
        int taskA = min(base + tA, kBNN - 1);
        f32x4 zz = {0.f, 0.f, 0.f, 0.f};
        f32x4 acc[4]; acc[0] = zz; acc[1] = zz; acc[2] = zz; acc[3] = zz;
#pragma unroll
        for (int s = 0; s < 2; ++s) {
            U4 raw; raw.u = *(const uint4*)&P2[(size_t)taskA * 64 + s * 32 + kg * 8];
            u32 w_[4];
#pragma unroll
            for (int p = 0; p < 4; ++p) {
                u32 word = (p < 2) ? ((p == 0) ? raw.u.x : raw.u.y) : ((p == 2) ? raw.u.z : raw.u.w);
                float t0 = fmaf(bflo(word), scA[s][2 * p],     shA[s][2 * p]);     t0 = t0 > 0.f ? t0 : 0.f;
                float t1 = fmaf(bfhi(word), scA[s][2 * p + 1], shA[s][2 * p + 1]); t1 = t1 > 0.f ? t1 : 0.f;
                w_[p] = packbf(t0, t1);
            }
            U4 a; a.u = make_uint4(w_[0], w_[1], w_[2], w_[3]);
#pragma unroll
            for (int nf = 0; nf < 4; ++nf) {
                int colb = nf * 16 + tA;
                U4 bb; bb.u = *(const uint4*)&Bl[((s * 4 + kg) * 64 + (colb ^ kg)) * 8];
                acc[nf] = __builtin_amdgcn_mfma_f32_16x16x32_bf16(a.h, bb.h, acc[nf], 0, 0, 0);
            }
        }
#pragma unroll
        for (int nf = 0; nf < 4; ++nf) {
#pragma unroll
            for (int r = 0; r < 4; ++r) {
                int task = base + kg * 4 + r;
                if (task < kBNN) {
                    float val = acc[nf][r] + bias_w[nf];
                    O[(size_t)task * 64 + nf * 16 + tA] = bf16r(val);
                    s_[nf] += val; sq_[nf] += val * val;
                }
            }
        }
    }
#pragma unroll
    for (int nf = 0; nf < 4; ++nf) {
        s_[nf]  += __shfl_xor(s_[nf], 16, 64);  s_[nf]  += __shfl_xor(s_[nf], 32, 64);
        sq_[nf] += __shfl_xor(sq_[nf], 16, 64); sq_[nf] += __shfl_xor(sq_[nf], 32, 64);
    }
    if (lane < 16) {
#pragma unroll
        for (int nf = 0; nf < 4; ++nf) {
            sred[wslot * 128 + nf * 16 + lane]      = s_[nf];
            sred[wslot * 128 + 64 + nf * 16 + lane] = sq_[nf];
        }
    }
    __syncthreads();
    if (wslot == 0) {
        float S = 0.f, SQ = 0.f;
#pragma unroll
        for (int w = 0; w < 8; ++w) {
            S  += sred[w * 128 + lane];
            SQ += sred[w * 128 + 64 + lane];
        }
        atomicAdd(&stats[lane], S);
        atomicAdd(&stats[64 + lane], SQ);
    }
}

// ---------------- final: relu(bn3(P3) + bns(S)) -> out (B,64,NV) channel-major ----------------
__global__ __launch_bounds__(256) void final_k(
    const u16* __restrict__ P3, const u16* __restrict__ S,
    const float* __restrict__ st3, const float* __restrict__ stS,
    const float* __restrict__ g3, const float* __restrict__ b3,
    const float* __restrict__ gs, const float* __restrict__ bs,
    float* __restrict__ out)
{
    __shared__ float lds[64 * 65];
    const int tilesPerB = (kNV + 63) / 64;  // 641
    int tile = blockIdx.x % tilesPerB;
    int b    = blockIdx.x / tilesPerB;
    int v0   = tile * 64;
    int tid  = threadIdx.x;
#pragma unroll
    for (int r = 0; r < 16; ++r) {
        int idx = r * 256 + tid;
        int vl = idx >> 6, o = idx & 63;
        int v = v0 + vl;
        if (v < kNV) {
            float m3  = st3[o] * kInvN;
            float vr3 = st3[64 + o] * kInvN - m3 * m3;
            float sc3 = g3[o] * rsqrtf(vr3 + kEPS);
            float sh3 = b3[o] - m3 * sc3;
            float mS  = stS[o] * kInvN;
            float vrS = stS[64 + o] * kInvN - mS * mS;
            float scS = gs[o] * rsqrtf(vrS + kEPS);
            float shS = bs[o] - mS * scS;
            size_t base = ((size_t)v * 2 + b) * 64 + o;
            float val = fmaf(b2f(P3[base]), sc3, sh3) + fmaf(b2f(S[base]), scS, shS);
            lds[vl * 65 + o] = val > 0.f ? val : 0.f;
        }
    }
    __syncthreads();
#pragma unroll
    for (int r = 0; r < 16; ++r) {
        int idx = r * 256 + tid;
        int o = idx >> 6, vl = idx & 63;
        int v = v0 + vl;
        if (v < kNV) out[(size_t)(b * 64 + o) * kNV + v] = lds[vl * 65 + o];
    }
}

extern "C" void kernel_launch(void* const* d_in, const int* in_sizes, int n_in,
                              void* d_out, int out_size, void* d_ws, size_t ws_size,
                              hipStream_t stream) {
    const float* x1  = (const float*)d_in[0];
    const float* x2  = (const float*)d_in[1];
    const int*   Gc  = (const int*)d_in[2];
    const float* Gv  = (const float*)d_in[3];
    const int*   Lc  = (const int*)d_in[4];
    const float* Lv  = (const float*)d_in[5];
    const int*   Fc  = (const int*)d_in[6];
    const float* Fv  = (const float*)d_in[7];
    const float* ew  = (const float*)d_in[8];
    const float* ns  = (const float*)d_in[9];
    // d_in[10] = v2p (identity arange, unused)
    const float* upC = (const float*)d_in[11];
    const float* upB = (const float*)d_in[12];
    const float* c2C = (const float*)d_in[13];
    const float* c2B = (const float*)d_in[14];
    const float* w1  = (const float*)d_in[15];
    const float* b1  = (const float*)d_in[16];
    const float* w3  = (const float*)d_in[17];
    const float* b3  = (const float*)d_in[18];
    const float* wsw = (const float*)d_in[19];
    const float* wsb = (const float*)d_in[20];
    const float* bn1g = (const float*)d_in[21];
    const float* bn1b = (const float*)d_in[22];
    const float* bn2g = (const float*)d_in[23];
    const float* bn2b = (const float*)d_in[24];
    const float* bn3g = (const float*)d_in[25];
    const float* bn3b = (const float*)d_in[26];
    const float* bnsg = (const float*)d_in[27];
    const float* bnsb = (const float*)d_in[28];

    float* ws = (float*)d_ws;
    float* stats = ws;  // [bn1|bn2|bn3|bns] x [sum64, sumsq64]
    size_t off = 512;
    u16* Xc    = (u16*)(ws + off); off += (size_t)kBNN * 64;   // bf16 (NV,B,128)
    u16* xin16 = (u16*)(ws + off); off += (size_t)kBNN * 32;   // bf16 (NV,B,64)
    u32* gegn  = (u32*)(ws + off); off += (size_t)kB * kNF * 64;  // (NF,B,64)
    u16* P1    = (u16*)(ws + off); off += (size_t)kBNN * 32;   // bf16 (NV,B,64)
    u16* Sbuf  = (u16*)(ws + off); off += (size_t)kBNN * 32;   // bf16
    u16* P2    = (u16*)(ws + off); off += (size_t)kBNN * 32;   // bf16
    u16* P3    = (u16*)(ws + off); off += (size_t)kBNN * 32;   // bf16
    uint4* faceTab = (uint4*)(ws + off); off += (size_t)kNF * 9 * 4;  // 11.8 MB
    u32* vtab  = (u32*)(ws + off); off += (size_t)kNV * 32;           // 5.2 MB
    u16* BgUp = (u16*)(ws + off); off += 256 * 64 / 2;                // 32 KB
    u16* BgC2 = (u16*)(ws + off); off += 256 * 64 / 2;                // 32 KB
    float* out = (float*)d_out;

    zero_stats_k<<<1, 512, 0, stream>>>(stats);
    build_facetab_k<<<(kNF * 9 + 255) / 256, 256, 0, stream>>>(Gc, Gv, ew, ns, faceTab);
    build_vtab_k<<<(kNV + 255) / 256, 256, 0, stream>>>(Lc, Lv, Fc, Fv, vtab);
    pack_coeffs_k<<<64, 256, 0, stream>>>(upC, BgUp);
    pack_coeffs_k<<<64, 256, 0, stream>>>(c2C, BgC2);
    transpose_in_k<<<2 * 641, 256, 0, stream>>>(x1, x2, xin16, Xc);
    // mesh_conv #1 (up) on xin (bf16): faces, fused gather+GEMM -> Xc[:,64:128]
    face_k<false><<<2560, 256, 0, stream>>>(xin16, faceTab,
                                            nullptr, nullptr, nullptr, gegn);
    vertex_fused_k<false, false, true><<<1280, 256, 0, stream>>>(
        xin16, gegn, vtab, (const uint4*)BgUp, upB,
        nullptr, nullptr, nullptr, (void*)(Xc + 64), 128, nullptr);
    // conv1 + convs on X = [x2, xu] (bf16)
    pconv_dual_k<<<512, 512, 0, stream>>>(Xc, w1, b1, wsw, wsb, P1, Sbuf,
                                          stats + 0 * 128, stats + 3 * 128);
    // mesh_conv #2 (c2) on h = relu(bn1(P1 bf16)), BN fused into consumers
    face_k<true><<<2560, 256, 0, stream>>>(P1, faceTab,
                                           stats + 0 * 128, bn1g, bn1b, gegn);
    vertex_fused_k<true, true, true><<<1280, 256, 0, stream>>>(
        P1, gegn, vtab, (const uint4*)BgC2, c2B,
        stats + 0 * 128, bn1g, bn1b, P2, 64, stats + 1 * 128);
    // conv3 on h2 = relu(bn2(P2 bf16)), BN fused into A-fragment build
    pconv3_k<<<512, 512, 0, stream>>>(P2, stats + 1 * 128, bn2g, bn2b,
                                      w3, b3, P3, stats + 2 * 128);
    final_k<<<2 * 641, 256, 0, stream>>>(P3, Sbuf, stats + 2 * 128, stats + 3 * 128,
                                         bn3g, bn3b, bnsg, bnsb, out);
}

// Round 14
// 250.022 us; speedup vs baseline: 1.0356x; 1.0356x over previous
//
#include <hip/hip_runtime.h>

typedef unsigned short u16;
typedef unsigned int u32;

constexpr int kNV  = 40962;
constexpr int kNF  = 81920;
constexpr int kNVP = 10242;
constexpr int kB   = 2;
constexpr float kEPS  = 1e-5f;
constexpr int kBNN   = kB * kNV;              // 81924
constexpr float kInvN = 1.0f / (float)kBNN;
constexpr int kTiles = (kBNN + 15) / 16;      // 5121

typedef __attribute__((ext_vector_type(8))) short bf16x8;
typedef __attribute__((ext_vector_type(4))) float f32x4;
union U4 { uint4 u; bf16x8 h; };

__device__ __forceinline__ float bflo(u32 u) { return __uint_as_float(u << 16); }
__device__ __forceinline__ float bfhi(u32 u) { return __uint_as_float(u & 0xffff0000u); }
__device__ __forceinline__ u32 packbf(float a, float b) {
    u32 ua = __float_as_uint(a), ub = __float_as_uint(b);
    ua += 0x7fffu + ((ua >> 16) & 1u);
    ub += 0x7fffu + ((ub >> 16) & 1u);
    return (ua >> 16) | (ub & 0xffff0000u);
}
__device__ __forceinline__ u16 bf16r(float a) {
    u32 ua = __float_as_uint(a);
    ua += 0x7fffu + ((ua >> 16) & 1u);
    return (u16)(ua >> 16);
}
__device__ __forceinline__ float b2f(u16 u) { return __uint_as_float(((u32)u) << 16); }

// Layout: batch-interleaved activations, row r = v*2+b (vertex) / rf = f*2+b (face).

// ---------------- fused prep: stats zero | face table | vertex table | 2x coeff pack ----------------
// block ranges: [0,2880) facetab, [2880,3041) vtab, [3041,3105) packUp, [3105,3169) packC2, 3169 zero
__global__ __launch_bounds__(256) void prep_k(
    const int* __restrict__ Gc, const float* __restrict__ Gv,
    const float* __restrict__ ew, const float* __restrict__ ns,
    const int* __restrict__ Lc, const float* __restrict__ Lv,
    const int* __restrict__ Fc, const float* __restrict__ Fv,
    const float* __restrict__ upC, const float* __restrict__ c2C,
    uint4* __restrict__ tab, u32* __restrict__ vtab,
    u16* __restrict__ BgUp, u16* __restrict__ BgC2, float* __restrict__ stats)
{
    int blk = blockIdx.x;
    if (blk < 2880) {
        int idx = blk * 256 + threadIdx.x;          // kNF*9 = 737280 total
        if (idx >= kNF * 9) return;
        int f = idx / 9, jk = idx - f * 9;
        int j = jk / 3, k = jk - j * 3;
        int r = j * kNF + f;
        float gv = Gv[r * 3 + k];
        tab[idx] = make_uint4((u32)Gc[r * 3 + k],
                              __float_as_uint(gv * ew[f * 3 + j]),
                              __float_as_uint(gv * ns[f * 3 + j]), 0u);
    } else if (blk < 3041) {
        int v = (blk - 2880) * 256 + threadIdx.x;
        if (v >= kNV) return;
        u32* d = vtab + (size_t)v * 32;
#pragma unroll
        for (int k = 0; k < 7; ++k) {
            d[k]      = (u32)Lc[v * 7 + k];
            d[16 + k] = __float_as_uint(Lv[v * 7 + k]);
        }
#pragma unroll
        for (int k = 0; k < 6; ++k) {
            d[7 + k]  = (u32)Fc[v * 6 + k];
            d[23 + k] = __float_as_uint(Fv[v * 6 + k]);
        }
        d[13] = 0; d[14] = 0; d[15] = 0;
        d[29] = 0; d[30] = 0; d[31] = 0;
    } else if (blk < 3169) {
        bool up = blk < 3105;
        int idx = (blk - (up ? 3041 : 3105)) * 256 + threadIdx.x;   // 256*64 total
        const float* coeffs = up ? upC : c2C;
        u16* Bg = up ? BgUp : BgC2;
        int k = idx >> 6, col = idx & 63;
        int s = k >> 5, kg = (k >> 3) & 3, jj = k & 7;
        Bg[((s * 4 + kg) * 64 + col) * 8 + jj] =
            bf16r(coeffs[((size_t)col * 64 + (k >> 2)) * 4 + (k & 3)]);
    } else {
        int t = threadIdx.x;
        if (t < 256) { stats[t] = 0.f; stats[256 + t] = 0.f; }
    }
}

// ---------------- tiled transpose: x1 -> xin16 (ones-pad) bf16, x2 -> Xc[:, :64] bf16 ----------------
__global__ __launch_bounds__(256) void transpose_in_k(const float* __restrict__ x1,
                                                      const float* __restrict__ x2,
                                                      u16* __restrict__ xin16,
                                                      u16* __restrict__ Xc) {
    __shared__ float t1[64 * 65];
    __shared__ float t2[64 * 65];
    const int tilesPerB = (kNV + 63) / 64;  // 641
    int tile = blockIdx.x % tilesPerB;
    int b    = blockIdx.x / tilesPerB;
    int v0   = tile * 64;
    int tid  = threadIdx.x;
    bool hasX1 = v0 < kNVP;
#pragma unroll
    for (int r = 0; r < 16; ++r) {
        int idx = r * 256 + tid;
        int c = idx >> 6, vl = idx & 63;
        int v = v0 + vl;
        if (v < kNV) {
            t2[vl * 65 + c] = x2[(size_t)(b * 64 + c) * kNV + v];
            if (hasX1) t1[vl * 65 + c] = (v < kNVP) ? x1[(size_t)(b * 64 + c) * kNVP + v] : 1.0f;
        }
    }
    __syncthreads();
#pragma unroll
    for (int r = 0; r < 16; ++r) {
        int idx = r * 256 + tid;
        int vl = idx >> 6, c = idx & 63;
        int v = v0 + vl;
        if (v < kNV) {
            Xc[((size_t)v * 2 + b) * 128 + c]   = bf16r(t2[vl * 65 + c]);
            xin16[((size_t)v * 2 + b) * 64 + c] = hasX1 ? bf16r(t1[vl * 65 + c]) : (u16)0x3f80;
        }
    }
}

// ---------------- face kernel: tasks rf=f*2+b, 4 tasks/p, 4ch/lane ----------------
template <bool BN>
__global__ __launch_bounds__(256) void face_k(
    const u16* __restrict__ src,                                     // (NV,B,64) bf16
    const uint4* __restrict__ tab,                                   // (NF*9)
    const float* __restrict__ st, const float* __restrict__ bg, const float* __restrict__ bb,
    u32* __restrict__ gegn)                                          // (NF,B,64) bf16x2
{
    int lane = threadIdx.x & 63;
    int q  = lane >> 4;
    int c0 = 4 * (lane & 15);
    int wave = blockIdx.x * 4 + (threadIdx.x >> 6);
    int nW   = gridDim.x * 4;
    float sc[4], sh[4];
    if constexpr (BN) {
#pragma unroll
        for (int j = 0; j < 4; ++j) {
            float m   = st[c0 + j] * kInvN;
            float var = st[64 + c0 + j] * kInvN - m * m;
            sc[j] = bg[c0 + j] * rsqrtf(var + kEPS);
            sh[j] = bb[c0 + j] - m * sc[j];
        }
    }
    const int nG = (kB * kNF) / 16;  // 10240, exact
    for (int g = wave; g < nG; g += nW) {
        int t0 = g * 16;
#pragma unroll
        for (int p = 0; p < 4; ++p) {
            int task = t0 + 4 * p + q;                // rf = f*2 + b
            int b = task & 1;
            int f = task >> 1;
            const uint4* tf = tab + (size_t)f * 9;
            float aE[4] = {0.f, 0.f, 0.f, 0.f}, aN[4] = {0.f, 0.f, 0.f, 0.f};
#pragma unroll
            for (int jk = 0; jk < 9; ++jk) {
                uint4 tb = tf[jk];
                float wE = __uint_as_float(tb.y), wN = __uint_as_float(tb.z);
                uint2 xv = *(const uint2*)&src[((size_t)tb.x * 2 + b) * 64 + c0];
                float x_[4] = {bflo(xv.x), bfhi(xv.x), bflo(xv.y), bfhi(xv.y)};
#pragma unroll
                for (int j = 0; j < 4; ++j) {
                    float x = x_[j];
                    if constexpr (BN) { x = fmaf(x, sc[j], sh[j]); x = x > 0.f ? x : 0.f; }
                    aE[j] = fmaf(wE, x, aE[j]);
                    aN[j] = fmaf(wN, x, aN[j]);
                }
            }
            *(uint4*)&gegn[(size_t)task * 64 + c0] =
                make_uint4(packbf(aE[0], aN[0]), packbf(aE[1], aN[1]),
                           packbf(aE[2], aN[2]), packbf(aE[3], aN[3]));
        }
    }
}

// ---------------- fused vertex kernel: tasks r=v*2+b, 2ch/lane gather -> feat LDS -> MFMA ----------------
template <bool STATS, bool BN, bool OUT16>
__global__ __launch_bounds__(256, 2) void vertex_fused_k(
    const u16* __restrict__ src,                                     // (NV,B,64) bf16
    const u32* __restrict__ gegn,                                    // (NF,B,64)
    const u32* __restrict__ vtab,                                    // (NV,32) packed idx/w
    const uint4* __restrict__ Bg,                                    // packed B fragments (32 KB)
    const float* __restrict__ bias,
    const float* __restrict__ st, const float* __restrict__ bg, const float* __restrict__ bbn,
    void* __restrict__ out_, int outStride, float* __restrict__ stats)
{
    __shared__ __align__(16) uint2 feat[4][16][64];   // 32 KB
    __shared__ float sred[STATS ? 4 * 128 : 4];
    int tid   = threadIdx.x;
    int lane  = tid & 63;
    int cl = lane & 31, half = lane >> 5;
    int c0 = 2 * cl;
    int wslot = tid >> 6;
    float sc0 = 0.f, sh0 = 0.f, sc1 = 0.f, sh1 = 0.f;
    if constexpr (BN) {
        float m0 = st[c0] * kInvN, m1 = st[c0 + 1] * kInvN;
        float v0 = st[64 + c0] * kInvN - m0 * m0;
        float v1 = st[64 + c0 + 1] * kInvN - m1 * m1;
        sc0 = bg[c0] * rsqrtf(v0 + kEPS);     sh0 = bbn[c0] - m0 * sc0;
        sc1 = bg[c0 + 1] * rsqrtf(v1 + kEPS); sh1 = bbn[c0 + 1] - m1 * sc1;
    }
    int tA = lane & 15, kg = lane >> 4;
    const int amask = (tA & 3) << 3;
    float bias_w[4];
#pragma unroll
    for (int nf = 0; nf < 4; ++nf) bias_w[nf] = bias[nf * 16 + tA];
    float s_[4] = {0.f, 0.f, 0.f, 0.f}, sq_[4] = {0.f, 0.f, 0.f, 0.f};

    int wave = blockIdx.x * 4 + wslot;
    int nW   = gridDim.x * 4;

    for (int tile = wave; tile < kTiles; tile += nW) {
        int base = tile * 16;
#pragma unroll 4
        for (int p = 0; p < 8; ++p) {
            int t = 2 * p + half;
            int task = base + t;                     // r = v*2 + b
            float x0 = 0.f, x1 = 0.f, l0 = 0.f, l1 = 0.f;
            float e0 = 0.f, e1 = 0.f, n0 = 0.f, n1 = 0.f;
            if (task < kBNN) {
                int b = task & 1;
                int v = task >> 1;
                const u32* vt = vtab + (size_t)v * 32;
                uint4  I0 = *(const uint4*)&vt[0];
                uint4  I1 = *(const uint4*)&vt[4];
                uint4  I2 = *(const uint4*)&vt[8];
                u32    I3 = vt[12];
                float4 W0 = *(const float4*)&vt[16];
                float4 W1 = *(const float4*)&vt[20];
                float4 W2 = *(const float4*)&vt[24];
                float  W3 = __uint_as_float(vt[28]);
                u32 Lcols[7] = {I0.x, I0.y, I0.z, I0.w, I1.x, I1.y, I1.z};
                float Lw[7]  = {W0.x, W0.y, W0.z, W0.w, W1.x, W1.y, W1.z};
                u32 Fcols[6] = {I1.w, I2.x, I2.y, I2.z, I2.w, I3};
                float Fw[6]  = {W1.w, W2.x, W2.y, W2.z, W2.w, W3};

                u32 xv = *(const u32*)&src[(size_t)task * 64 + c0];
                x0 = bflo(xv); x1 = bfhi(xv);
                if constexpr (BN) {
                    x0 = fmaf(x0, sc0, sh0); x0 = x0 > 0.f ? x0 : 0.f;
                    x1 = fmaf(x1, sc1, sh1); x1 = x1 > 0.f ? x1 : 0.f;
                }
#pragma unroll
                for (int k = 0; k < 7; ++k) {
                    u32 lv = *(const u32*)&src[((size_t)Lcols[k] * 2 + b) * 64 + c0];
                    float w = Lw[k];
                    float y0 = bflo(lv), y1 = bfhi(lv);
                    if constexpr (BN) {
                        y0 = fmaf(y0, sc0, sh0); y0 = y0 > 0.f ? y0 : 0.f;
                        y1 = fmaf(y1, sc1, sh1); y1 = y1 > 0.f ? y1 : 0.f;
                    }
                    l0 = fmaf(w, y0, l0); l1 = fmaf(w, y1, l1);
                }
#pragma unroll
                for (int k = 0; k < 6; ++k) {
                    uint2 gv = *(const uint2*)&gegn[((size_t)Fcols[k] * 2 + b) * 64 + c0];
                    float w = Fw[k];
                    e0 = fmaf(w, bflo(gv.x), e0); n0 = fmaf(w, bfhi(gv.x), n0);
                    e1 = fmaf(w, bflo(gv.y), e1); n1 = fmaf(w, bfhi(gv.y), n1);
                }
            }
            int cs = c0 ^ ((t & 3) << 3);
            *(uint4*)&feat[wslot][t][cs] =
                make_uint4(packbf(x0, l0), packbf(e0, n0), packbf(x1, l1), packbf(e1, n1));
        }
        f32x4 z = {0.f, 0.f, 0.f, 0.f};
        f32x4 acc[4]; acc[0] = z; acc[1] = z; acc[2] = z; acc[3] = z;
#pragma unroll
        for (int sl = 0; sl < 8; ++sl) {
            int i0 = sl * 8 + kg * 2;
            U4 a; a.u = *(const uint4*)&feat[wslot][tA][i0 ^ amask];
#pragma unroll
            for (int nf = 0; nf < 4; ++nf) {
                U4 bb; bb.u = Bg[(sl * 4 + kg) * 64 + nf * 16 + tA];
                acc[nf] = __builtin_amdgcn_mfma_f32_16x16x32_bf16(a.h, bb.h, acc[nf], 0, 0, 0);
            }
        }
#pragma unroll
        for (int nf = 0; nf < 4; ++nf) {
#pragma unroll
            for (int r = 0; r < 4; ++r) {
                int task = base + kg * 4 + r;
                if (task < kBNN) {
                    float val = acc[nf][r] + bias_w[nf];
                    int col = nf * 16 + tA;
                    if constexpr (OUT16)
                        ((u16*)out_)[(size_t)task * outStride + col] = bf16r(val);
                    else
                        ((float*)out_)[(size_t)task * outStride + col] = val;
                    if constexpr (STATS) { s_[nf] += val; sq_[nf] += val * val; }
                }
            }
        }
    }
    if constexpr (STATS) {
#pragma unroll
        for (int nf = 0; nf < 4; ++nf) {
            s_[nf]  += __shfl_xor(s_[nf], 16, 64);  s_[nf]  += __shfl_xor(s_[nf], 32, 64);
            sq_[nf] += __shfl_xor(sq_[nf], 16, 64); sq_[nf] += __shfl_xor(sq_[nf], 32, 64);
        }
        if (lane < 16) {
#pragma unroll
            for (int nf = 0; nf < 4; ++nf) {
                sred[wslot * 128 + nf * 16 + lane]      = s_[nf];
                sred[wslot * 128 + 64 + nf * 16 + lane] = sq_[nf];
            }
        }
        __syncthreads();
        if (wslot == 0) {
            float S = 0.f, SQ = 0.f;
#pragma unroll
            for (int w = 0; w < 4; ++w) {
                S  += sred[w * 128 + lane];
                SQ += sred[w * 128 + 64 + lane];
            }
            atomicAdd(&stats[lane], S);
            atomicAdd(&stats[64 + lane], SQ);
        }
    }
}

// ---------------- conv1+convs fused: A=Xc bf16 global, N=128 (64|64), K=128, MFMA ----------------
__global__ __launch_bounds__(512) void pconv_dual_k(
    const u16* __restrict__ Xc,
    const float* __restrict__ W1, const float* __restrict__ b1,
    const float* __restrict__ W2, const float* __restrict__ b2,
    u16* __restrict__ O1, u16* __restrict__ O2,
    float* __restrict__ stats1, float* __restrict__ stats2)
{
    __shared__ __align__(16) u16 Bl[128 * 128];   // 32 KB
    __shared__ float sred[8 * 256];
    int tid = threadIdx.x;
    for (int idx = tid; idx < 128 * 128; idx += 512) {
        int k = idx >> 7, col = idx & 127;
        int s = k >> 5, kg = (k >> 3) & 3, jj = k & 7;
        float v = (col < 64) ? W1[(size_t)col * 128 + k] : W2[(size_t)(col - 64) * 128 + k];
        Bl[((s * 4 + kg) * 128 + (col ^ kg)) * 8 + jj] = bf16r(v);
    }
    __syncthreads();

    int lane = tid & 63, wslot = tid >> 6;
    int tA = lane & 15, kg = lane >> 4;
    float bias_w[8];
#pragma unroll
    for (int nf = 0; nf < 8; ++nf)
        bias_w[nf] = (nf < 4) ? b1[nf * 16 + tA] : b2[(nf - 4) * 16 + tA];
    float s_[8] = {0.f}, sq_[8] = {0.f};

    int wave = blockIdx.x * 8 + wslot;
    int nW   = gridDim.x * 8;
    for (int tile = wave; tile < kTiles; tile += nW) {
        int base = tile * 16;
        int taskA = min(base + tA, kBNN - 1);
        f32x4 zz = {0.f, 0.f, 0.f, 0.f};
        f32x4 acc[8];
#pragma unroll
        for (int nf = 0; nf < 8; ++nf) acc[nf] = zz;
#pragma unroll
        for (int s = 0; s < 4; ++s) {
            U4 a; a.u = *(const uint4*)&Xc[(size_t)taskA * 128 + s * 32 + kg * 8];
#pragma unroll
            for (int nf = 0; nf < 8; ++nf) {
                int colb = nf * 16 + tA;
                U4 bb; bb.u = *(const uint4*)&Bl[((s * 4 + kg) * 128 + (colb ^ kg)) * 8];
                acc[nf] = __builtin_amdgcn_mfma_f32_16x16x32_bf16(a.h, bb.h, acc[nf], 0, 0, 0);
            }
        }
#pragma unroll
        for (int nf = 0; nf < 8; ++nf) {
#pragma unroll
            for (int r = 0; r < 4; ++r) {
                int task = base + kg * 4 + r;
                if (task < kBNN) {
                    float val = acc[nf][r] + bias_w[nf];
                    if (nf < 4) O1[(size_t)task * 64 + nf * 16 + tA] = bf16r(val);
                    else        O2[(size_t)task * 64 + (nf - 4) * 16 + tA] = bf16r(val);
                    s_[nf] += val; sq_[nf] += val * val;
                }
            }
        }
    }
#pragma unroll
    for (int nf = 0; nf < 8; ++nf) {
        s_[nf]  += __shfl_xor(s_[nf], 16, 64);  s_[nf]  += __shfl_xor(s_[nf], 32, 64);
        sq_[nf] += __shfl_xor(sq_[nf], 16, 64); sq_[nf] += __shfl_xor(sq_[nf], 32, 64);
    }
    if (lane < 16) {
#pragma unroll
        for (int nf = 0; nf < 8; ++nf) {
            sred[wslot * 256 + nf * 16 + lane]       = s_[nf];
            sred[wslot * 256 + 128 + nf * 16 + lane] = sq_[nf];
        }
    }
    __syncthreads();
    if (wslot == 0) {
        float S = 0.f, SQ = 0.f;
#pragma unroll
        for (int w = 0; w < 8; ++w) {
            S  += sred[w * 256 + lane];
            SQ += sred[w * 256 + 128 + lane];
        }
        atomicAdd(&stats1[lane], S);
        atomicAdd(&stats1[64 + lane], SQ);
    } else if (wslot == 1) {
        float S = 0.f, SQ = 0.f;
#pragma unroll
        for (int w = 0; w < 8; ++w) {
            S  += sred[w * 256 + 64 + lane];
            SQ += sred[w * 256 + 128 + 64 + lane];
        }
        atomicAdd(&stats2[lane], S);
        atomicAdd(&stats2[64 + lane], SQ);
    }
}

// ---------------- conv3: A = relu(bn2(P2 bf16)) on the fly, K=64, N=64, MFMA ----------------
__global__ __launch_bounds__(512) void pconv3_k(
    const u16* __restrict__ P2,
    const float* __restrict__ st2, const float* __restrict__ g2, const float* __restrict__ b2n,
    const float* __restrict__ W, const float* __restrict__ bW,
    u16* __restrict__ O, float* __restrict__ stats)
{
    __shared__ __align__(16) u16 Bl[64 * 64];   // 8 KB
    __shared__ float sred[8 * 128];
    int tid = threadIdx.x;
    for (int idx = tid; idx < 64 * 64; idx += 512) {
        int k = idx >> 6, col = idx & 63;
        int s = k >> 5, kg = (k >> 3) & 3, jj = k & 7;
        Bl[((s * 4 + kg) * 64 + (col ^ kg)) * 8 + jj] = bf16r(W[(size_t)col * 64 + k]);
    }
    __syncthreads();

    int lane = tid & 63, wslot = tid >> 6;
    int tA = lane & 15, kg = lane >> 4;
    float scA[2][8], shA[2][8];
#pragma unroll
    for (int s = 0; s < 2; ++s)
#pragma unroll
        for (int j = 0; j < 8; ++j) {
            int ch = s * 32 + kg * 8 + j;
            float m   = st2[ch] * kInvN;
            float var = st2[64 + ch] * kInvN - m * m;
            float sc  = g2[ch] * rsqrtf(var + kEPS);
            scA[s][j] = sc;
            shA[s][j] = b2n[ch] - m * sc;
        }
    float bias_w[4];
#pragma unroll
    for (int nf = 0; nf < 4; ++nf) bias_w[nf] = bW[nf * 16 + tA];
    float s_[4] = {0.f}, sq_[4] = {0.f};

    int wave = blockIdx.x * 8 + wslot;
    int nW   = gridDim.x * 8;
    for (int tile = wave; tile < kTiles; tile += nW) {
        int base = tile * 16;
        int taskA = min(base + tA, kBNN - 1);
        f32x4 zz = {0.f, 0.f, 0.f, 0.f};
        f32x4 acc[4]; acc[0] = zz; acc[1] = zz; acc[2] = zz; acc[3] = zz;
#pragma unroll
        for (int s = 0; s < 2; ++s) {
            U4 raw; raw.u = *(const uint4*)&P2[(size_t)taskA * 64 + s * 32 + kg * 8];
            u32 w_[4];
#pragma unroll
            for (int p = 0; p < 4; ++p) {
                u32 word = (p < 2) ? ((p == 0) ? raw.u.x : raw.u.y) : ((p == 2) ? raw.u.z : raw.u.w);
                float t0 = fmaf(bflo(word), scA[s][2 * p],     shA[s][2 * p]);     t0 = t0 > 0.f ? t0 : 0.f;
                float t1 = fmaf(bfhi(word), scA[s][2 * p + 1], shA[s][2 * p + 1]); t1 = t1 > 0.f ? t1 : 0.f;
                w_[p] = packbf(t0, t1);
            }
            U4 a; a.u = make_uint4(w_[0], w_[1], w_[2], w_[3]);
#pragma unroll
            for (int nf = 0; nf < 4; ++nf) {
                int colb = nf * 16 + tA;
                U4 bb; bb.u = *(const uint4*)&Bl[((s * 4 + kg) * 64 + (colb ^ kg)) * 8];
                acc[nf] = __builtin_amdgcn_mfma_f32_16x16x32_bf16(a.h, bb.h, acc[nf], 0, 0, 0);
            }
        }
#pragma unroll
        for (int nf = 0; nf < 4; ++nf) {
#pragma unroll
            for (int r = 0; r < 4; ++r) {
                int task = base + kg * 4 + r;
                if (task < kBNN) {
                    float val = acc[nf][r] + bias_w[nf];
                    O[(size_t)task * 64 + nf * 16 + tA] = bf16r(val);
                    s_[nf] += val; sq_[nf] += val * val;
                }
            }
        }
    }
#pragma unroll
    for (int nf = 0; nf < 4; ++nf) {
        s_[nf]  += __shfl_xor(s_[nf], 16, 64);  s_[nf]  += __shfl_xor(s_[nf], 32, 64);
        sq_[nf] += __shfl_xor(sq_[nf], 16, 64); sq_[nf] += __shfl_xor(sq_[nf], 32, 64);
    }
    if (lane < 16) {
#pragma unroll
        for (int nf = 0; nf < 4; ++nf) {
            sred[wslot * 128 + nf * 16 + lane]      = s_[nf];
            sred[wslot * 128 + 64 + nf * 16 + lane] = sq_[nf];
        }
    }
    __syncthreads();
    if (wslot == 0) {
        float S = 0.f, SQ = 0.f;
#pragma unroll
        for (int w = 0; w < 8; ++w) {
            S  += sred[w * 128 + lane];
            SQ += sred[w * 128 + 64 + lane];
        }
        atomicAdd(&stats[lane], S);
        atomicAdd(&stats[64 + lane], SQ);
    }
}

// ---------------- final: relu(bn3(P3) + bns(S)) -> out (B,64,NV) channel-major ----------------
__global__ __launch_bounds__(256) void final_k(
    const u16* __restrict__ P3, const u16* __restrict__ S,
    const float* __restrict__ st3, const float* __restrict__ stS,
    const float* __restrict__ g3, const float* __restrict__ b3,
    const float* __restrict__ gs, const float* __restrict__ bs,
    float* __restrict__ out)
{
    __shared__ float lds[64 * 65];
    const int tilesPerB = (kNV + 63) / 64;  // 641
    int tile = blockIdx.x % tilesPerB;
    int b    = blockIdx.x / tilesPerB;
    int v0   = tile * 64;
    int tid  = threadIdx.x;
#pragma unroll
    for (int r = 0; r < 16; ++r) {
        int idx = r * 256 + tid;
        int vl = idx >> 6, o = idx & 63;
        int v = v0 + vl;
        if (v < kNV) {
            float m3  = st3[o] * kInvN;
            float vr3 = st3[64 + o] * kInvN - m3 * m3;
            float sc3 = g3[o] * rsqrtf(vr3 + kEPS);
            float sh3 = b3[o] - m3 * sc3;
            float mS  = stS[o] * kInvN;
            float vrS = stS[64 + o] * kInvN - mS * mS;
            float scS = gs[o] * rsqrtf(vrS + kEPS);
            float shS = bs[o] - mS * scS;
            size_t base = ((size_t)v * 2 + b) * 64 + o;
            float val = fmaf(b2f(P3[base]), sc3, sh3) + fmaf(b2f(S[base]), scS, shS);
            lds[vl * 65 + o] = val > 0.f ? val : 0.f;
        }
    }
    __syncthreads();
#pragma unroll
    for (int r = 0; r < 16; ++r) {
        int idx = r * 256 + tid;
        int o = idx >> 6, vl = idx & 63;
        int v = v0 + vl;
        if (v < kNV) out[(size_t)(b * 64 + o) * kNV + v] = lds[vl * 65 + o];
    }
}

extern "C" void kernel_launch(void* const* d_in, const int* in_sizes, int n_in,
                              void* d_out, int out_size, void* d_ws, size_t ws_size,
                              hipStream_t stream) {
    const float* x1  = (const float*)d_in[0];
    const float* x2  = (const float*)d_in[1];
    const int*   Gc  = (const int*)d_in[2];
    const float* Gv  = (const float*)d_in[3];
    const int*   Lc  = (const int*)d_in[4];
    const float* Lv  = (const float*)d_in[5];
    const int*   Fc  = (const int*)d_in[6];
    const float* Fv  = (const float*)d_in[7];
    const float* ew  = (const float*)d_in[8];
    const float* ns  = (const float*)d_in[9];
    // d_in[10] = v2p (identity arange, unused)
    const float* upC = (const float*)d_in[11];
    const float* upB = (const float*)d_in[12];
    const float* c2C = (const float*)d_in[13];
    const float* c2B = (const float*)d_in[14];
    const float* w1  = (const float*)d_in[15];
    const float* b1  = (const float*)d_in[16];
    const float* w3  = (const float*)d_in[17];
    const float* b3  = (const float*)d_in[18];
    const float* wsw = (const float*)d_in[19];
    const float* wsb = (const float*)d_in[20];
    const float* bn1g = (const float*)d_in[21];
    const float* bn1b = (const float*)d_in[22];
    const float* bn2g = (const float*)d_in[23];
    const float* bn2b = (const float*)d_in[24];
    const float* bn3g = (const float*)d_in[25];
    const float* bn3b = (const float*)d_in[26];
    const float* bnsg = (const float*)d_in[27];
    const float* bnsb = (const float*)d_in[28];

    float* ws = (float*)d_ws;
    float* stats = ws;  // [bn1|bn2|bn3|bns] x [sum64, sumsq64]
    size_t off = 512;
    u16* Xc    = (u16*)(ws + off); off += (size_t)kBNN * 64;   // bf16 (NV,B,128)
    u16* xin16 = (u16*)(ws + off); off += (size_t)kBNN * 32;   // bf16 (NV,B,64)
    u32* gegn  = (u32*)(ws + off); off += (size_t)kB * kNF * 64;  // (NF,B,64)
    u16* P1    = (u16*)(ws + off); off += (size_t)kBNN * 32;   // bf16 (NV,B,64)
    u16* Sbuf  = (u16*)(ws + off); off += (size_t)kBNN * 32;   // bf16
    u16* P2    = (u16*)(ws + off); off += (size_t)kBNN * 32;   // bf16
    u16* P3    = (u16*)(ws + off); off += (size_t)kBNN * 32;   // bf16
    uint4* faceTab = (uint4*)(ws + off); off += (size_t)kNF * 9 * 4;  // 11.8 MB
    u32* vtab  = (u32*)(ws + off); off += (size_t)kNV * 32;           // 5.2 MB
    u16* BgUp = (u16*)(ws + off); off += 256 * 64 / 2;                // 32 KB
    u16* BgC2 = (u16*)(ws + off); off += 256 * 64 / 2;                // 32 KB
    float* out = (float*)d_out;

    // one fused prep kernel (facetab | vtab | coeff packs | stats zero)
    prep_k<<<3170, 256, 0, stream>>>(Gc, Gv, ew, ns, Lc, Lv, Fc, Fv, upC, c2C,
                                     faceTab, vtab, BgUp, BgC2, stats);
    transpose_in_k<<<2 * 641, 256, 0, stream>>>(x1, x2, xin16, Xc);
    // mesh_conv #1 (up) on xin (bf16): faces, fused gather+GEMM -> Xc[:,64:128]
    face_k<false><<<2560, 256, 0, stream>>>(xin16, faceTab,
                                            nullptr, nullptr, nullptr, gegn);
    vertex_fused_k<false, false, true><<<1280, 256, 0, stream>>>(
        xin16, gegn, vtab, (const uint4*)BgUp, upB,
        nullptr, nullptr, nullptr, (void*)(Xc + 64), 128, nullptr);
    // conv1 + convs on X = [x2, xu] (bf16)
    pconv_dual_k<<<512, 512, 0, stream>>>(Xc, w1, b1, wsw, wsb, P1, Sbuf,
                                          stats + 0 * 128, stats + 3 * 128);
    // mesh_conv #2 (c2) on h = relu(bn1(P1 bf16)), BN fused into consumers
    face_k<true><<<2560, 256, 0, stream>>>(P1, faceTab,
                                           stats + 0 * 128, bn1g, bn1b, gegn);
    vertex_fused_k<true, true, true><<<1280, 256, 0, stream>>>(
        P1, gegn, vtab, (const uint4*)BgC2, c2B,
        stats + 0 * 128, bn1g, bn1b, P2, 64, stats + 1 * 128);
    // conv3 on h2 = relu(bn2(P2 bf16)), BN fused into A-fragment build
    pconv3_k<<<512, 512, 0, stream>>>(P2, stats + 1 * 128, bn2g, bn2b,
                                      w3, b3, P3, stats + 2 * 128);
    final_k<<<2 * 641, 256, 0, stream>>>(P3, Sbuf, stats + 2 * 128, stats + 3 * 128,
                                         bn3g, bn3b, bnsg, bnsb, out);
}